// Round 1
// baseline (1028.846 us; speedup 1.0000x reference)
//
#include <hip/hip_runtime.h>
#include <hip/hip_bf16.h>
#include <math.h>

// Problem constants
#define BATCH 64
#define TSTEP 20
#define FDIM  2048
#define EDIM  512
#define GDIM  1024
#define G3    3072
#define VDIM  32000

typedef __attribute__((ext_vector_type(8))) short short8x;
typedef __attribute__((ext_vector_type(4))) float f32x4;

static __device__ __forceinline__ unsigned short f2bf(float f) {
    unsigned int u = __float_as_uint(f);
    unsigned int r = (u + 0x7fffu + ((u >> 16) & 1u)) >> 16;
    return (unsigned short)r;
}

// ---------------------------------------------------------------------------
// scale_img[e] = img_g[e]/||img_v[e,:]||  (512 rows, one wave each)
// ---------------------------------------------------------------------------
__global__ __launch_bounds__(256) void scales_img_kernel(
    const float* __restrict__ img_v, const float* __restrict__ img_g,
    float* __restrict__ scale_img)
{
    int wave = blockIdx.x * 4 + (threadIdx.x >> 6);
    int lane = threadIdx.x & 63;
    const float* row = img_v + (size_t)wave * FDIM;
    float s = 0.f;
    for (int k = lane; k < FDIM; k += 64) { float v = row[k]; s = fmaf(v, v, s); }
    for (int off = 32; off; off >>= 1) s += __shfl_down(s, off);
    if (lane == 0) scale_img[wave] = img_g[wave] * (1.0f / sqrtf(s));
}

// ---------------------------------------------------------------------------
// fc row norm + bf16 convert fused: one block per row of fc_v [V,1024]
// ---------------------------------------------------------------------------
__global__ __launch_bounds__(256) void fc_norm_cvt_kernel(
    const float* __restrict__ fc_v, const float* __restrict__ fc_g,
    short* __restrict__ v_bf, float* __restrict__ scale_fc)
{
    int row = blockIdx.x;
    int t = threadIdx.x;
    float4 v = ((const float4*)(fc_v + (size_t)row * GDIM))[t];
    short4 o;
    o.x = (short)f2bf(v.x); o.y = (short)f2bf(v.y);
    o.z = (short)f2bf(v.z); o.w = (short)f2bf(v.w);
    ((short4*)(v_bf + (size_t)row * GDIM))[t] = o;
    float ss = v.x * v.x + v.y * v.y + v.z * v.z + v.w * v.w;
    for (int off = 32; off; off >>= 1) ss += __shfl_down(ss, off);
    __shared__ float red[4];
    if ((t & 63) == 0) red[t >> 6] = ss;
    __syncthreads();
    if (t == 0) {
        float s = red[0] + red[1] + red[2] + red[3];
        scale_fc[row] = fc_g[row] * (1.0f / sqrtf(s));
    }
}

// ---------------------------------------------------------------------------
// generic fp32 -> bf16 convert (n must be divisible by 4)
// ---------------------------------------------------------------------------
__global__ __launch_bounds__(256) void cvt_bf16_kernel(
    const float* __restrict__ in, short* __restrict__ out, int n4)
{
    int i = blockIdx.x * 256 + threadIdx.x;
    if (i >= n4) return;
    float4 v = ((const float4*)in)[i];
    short4 o;
    o.x = (short)f2bf(v.x); o.y = (short)f2bf(v.y);
    o.z = (short)f2bf(v.z); o.w = (short)f2bf(v.w);
    ((short4*)out)[i] = o;
}

// ---------------------------------------------------------------------------
// img_embed: x_all[0][b][e] = dot(features[b,:], img_v[e,:]) * scale_img[e] + img_b[e]
// ---------------------------------------------------------------------------
__global__ __launch_bounds__(256) void img_embed_kernel(
    const float* __restrict__ features, const float* __restrict__ img_v,
    const float* __restrict__ scale_img, const float* __restrict__ img_b,
    float* __restrict__ x_all)
{
    int wave = blockIdx.x * 4 + (threadIdx.x >> 6);
    int lane = threadIdx.x & 63;
    int b = wave >> 9;
    int e = wave & 511;
    const float* frow = features + (size_t)b * FDIM;
    const float* vrow = img_v + (size_t)e * FDIM;
    float s = 0.f;
    for (int k = lane; k < FDIM; k += 64) s = fmaf(frow[k], vrow[k], s);
    for (int off = 32; off; off >>= 1) s += __shfl_down(s, off);
    if (lane == 0) x_all[b * EDIM + e] = s * scale_img[e] + img_b[e];
}

// ---------------------------------------------------------------------------
// gather: x_all[t][b][:] = emb_table[input_ids[b][t]] for t = 1..19
// ---------------------------------------------------------------------------
__global__ __launch_bounds__(256) void gather_kernel(
    const int* __restrict__ ids, const float* __restrict__ emb,
    float* __restrict__ x_all)
{
    int idx = blockIdx.x * 256 + threadIdx.x;
    int e = idx & 511;
    int b = (idx >> 9) & 63;
    int t = (idx >> 15) + 1;
    int id = ids[b * TSTEP + t];
    x_all[(size_t)(t * BATCH + b) * EDIM + e] = emb[(size_t)id * EDIM + e];
}

// ---------------------------------------------------------------------------
// bf16 MFMA GEMM, 128x128 tile (kept for the small gi GEMM). See notes in
// mfma_gemm256_kernel for the structure; this is the prior verified kernel.
// ---------------------------------------------------------------------------
__global__ __launch_bounds__(256) void mfma_gemm_kernel(
    const short* __restrict__ A, const short* __restrict__ B,
    float* __restrict__ C, int M, int N, int K,
    const float* __restrict__ scale, const float* __restrict__ bias,
    int out_mode)
{
    __shared__ short As[128 * 32];
    __shared__ short Bs[128 * 32];

    const int tid  = threadIdx.x;
    const int wave = tid >> 6;
    const int lane = tid & 63;
    const int m0 = blockIdx.y * 128;
    const int n0 = blockIdx.x * 128;

    const int srow   = lane >> 2;
    const int schunk = (lane & 3) ^ ((lane >> 3) & 3);

    const int wm = wave >> 1, wn = wave & 1;
    const int fr = lane & 15;
    const int q  = lane >> 4;
    const int kchunk = (q ^ ((fr >> 1) & 3)) * 8;

    f32x4 acc[4][4];
    #pragma unroll
    for (int i = 0; i < 4; ++i)
        #pragma unroll
        for (int j = 0; j < 4; ++j)
            acc[i][j] = (f32x4)(0.f);

    for (int k0 = 0; k0 < K; k0 += 32) {
        __syncthreads();
        #pragma unroll
        for (int p = 0; p < 2; ++p) {
            int mi = wave * 2 + p;
            int rA = mi * 16 + srow;
            const short* gA = A + (size_t)(m0 + rA) * K + k0 + schunk * 8;
            const short* gB = B + (size_t)(n0 + rA) * K + k0 + schunk * 8;
            __builtin_amdgcn_global_load_lds(
                (const __attribute__((address_space(1))) void*)gA,
                (__attribute__((address_space(3))) void*)(As + mi * 512), 16, 0, 0);
            __builtin_amdgcn_global_load_lds(
                (const __attribute__((address_space(1))) void*)gB,
                (__attribute__((address_space(3))) void*)(Bs + mi * 512), 16, 0, 0);
        }
        __syncthreads();

        short8x a[4], b[4];
        #pragma unroll
        for (int i = 0; i < 4; ++i)
            a[i] = *(const short8x*)(As + (wm * 64 + i * 16 + fr) * 32 + kchunk);
        #pragma unroll
        for (int j = 0; j < 4; ++j)
            b[j] = *(const short8x*)(Bs + (wn * 64 + j * 16 + fr) * 32 + kchunk);
        #pragma unroll
        for (int i = 0; i < 4; ++i)
            #pragma unroll
            for (int j = 0; j < 4; ++j)
                acc[i][j] = __builtin_amdgcn_mfma_f32_16x16x32_bf16(a[i], b[j], acc[i][j], 0, 0, 0);
    }

    #pragma unroll
    for (int i = 0; i < 4; ++i) {
        #pragma unroll
        for (int r = 0; r < 4; ++r) {
            int m = m0 + wm * 64 + i * 16 + q * 4 + r;
            #pragma unroll
            for (int j = 0; j < 4; ++j) {
                int n = n0 + wn * 64 + j * 16 + fr;
                float v = acc[i][j][r];
                if (scale) v *= scale[n];
                if (bias)  v += bias[n];
                if (out_mode == 0) {
                    C[(size_t)m * N + n] = v;
                } else {
                    C[(size_t)(m & 63) * (TSTEP * N) + (size_t)(m >> 6) * N + n] = v;
                }
            }
        }
    }
}

// ---------------------------------------------------------------------------
// bf16 MFMA GEMM, 256x256 tile, BK=64, 512 threads (8 waves, 2m x 4n), 2-phase
// double-buffered pipeline: issue next-tile global_load_lds BEFORE ds_read+MFMA
// of current tile, single vmcnt-drain+barrier per K-step (T3-minimum).
// LDS rows are 128B => full 3-bit chunk swizzle c ^= (row&7): each 16-lane
// ds_read_b128 phase covers all 8 bank groups (2 lanes/bank = free). Swizzle
// is applied on the pre-swizzled GLOBAL source (gload_lds dest is linear) and
// on the ds_read address (both-sides rule). XCD-bijective block swizzle with
// m-fastest ordering so each XCD's L2 reuses one B panel across all 5 m-tiles.
// ---------------------------------------------------------------------------
__global__ __launch_bounds__(512, 2) void mfma_gemm256_kernel(
    const short* __restrict__ A, const short* __restrict__ B,
    float* __restrict__ C, int M, int N, int K,
    const float* __restrict__ scale, const float* __restrict__ bias,
    int out_mode)
{
    __shared__ short As[2][256 * 64];
    __shared__ short Bs[2][256 * 64];

    const int tid = threadIdx.x;
    const int mtiles = M >> 8;
    const int nwg = gridDim.x;

    // bijective XCD swizzle (8 XCDs), m-fastest tile order
    int wgid;
    {
        int q = nwg >> 3, r = nwg & 7;
        int xcd = blockIdx.x & 7, idx = blockIdx.x >> 3;
        wgid = (xcd < r ? xcd * (q + 1) : r * (q + 1) + (xcd - r) * q) + idx;
    }
    const int mt = wgid % mtiles;
    const int nt = wgid / mtiles;
    const int m0 = mt << 8, n0 = nt << 8;

    // staging addressing: thread covers (row = tid>>3 (+64/round), chunk = tid&7)
    // source chunk pre-swizzled so linear LDS holds swizzled layout
    const int schunk = (tid & 7) ^ ((tid >> 3) & 7);
    const short* gA = A + (size_t)(m0 + (tid >> 3)) * K + schunk * 8;
    const short* gB = B + (size_t)(n0 + (tid >> 3)) * K + schunk * 8;

    const int wv = tid >> 6, lane = tid & 63;
    const int sbase = wv * 512;              // wave-uniform LDS stage base (shorts)

    const int wm = wv >> 2, wn = wv & 3;     // 2 m-waves x 4 n-waves
    const int fr = lane & 15, qd = lane >> 4;
    const int key = fr & 7;
    int aoff[2], boff[2];
    #pragma unroll
    for (int kk = 0; kk < 2; ++kk) {
        int slot = ((kk << 2) | qd) ^ key;
        aoff[kk] = (wm * 128 + fr) * 64 + (slot << 3);
        boff[kk] = (wn * 64 + fr) * 64 + (slot << 3);
    }

    f32x4 acc[8][4];
    #pragma unroll
    for (int i = 0; i < 8; ++i)
        #pragma unroll
        for (int j = 0; j < 4; ++j)
            acc[i][j] = (f32x4)(0.f);

    auto stage = [&](int buf, int koff) {
        #pragma unroll
        for (int rho = 0; rho < 4; ++rho) {
            __builtin_amdgcn_global_load_lds(
                (const __attribute__((address_space(1))) void*)(gA + (size_t)(rho * 64) * K + koff),
                (__attribute__((address_space(3))) void*)(&As[buf][0] + rho * 4096 + sbase), 16, 0, 0);
            __builtin_amdgcn_global_load_lds(
                (const __attribute__((address_space(1))) void*)(gB + (size_t)(rho * 64) * K + koff),
                (__attribute__((address_space(3))) void*)(&Bs[buf][0] + rho * 4096 + sbase), 16, 0, 0);
        }
    };

    auto compute = [&](int buf) {
        const short* Ab = &As[buf][0];
        const short* Bb = &Bs[buf][0];
        #pragma unroll
        for (int kk = 0; kk < 2; ++kk) {
            short8x a[8], b[4];
            #pragma unroll
            for (int i = 0; i < 8; ++i) a[i] = *(const short8x*)(Ab + aoff[kk] + i * 1024);
            #pragma unroll
            for (int j = 0; j < 4; ++j) b[j] = *(const short8x*)(Bb + boff[kk] + j * 1024);
            __builtin_amdgcn_s_setprio(1);
            #pragma unroll
            for (int i = 0; i < 8; ++i)
                #pragma unroll
                for (int j = 0; j < 4; ++j)
                    acc[i][j] = __builtin_amdgcn_mfma_f32_16x16x32_bf16(a[i], b[j], acc[i][j], 0, 0, 0);
            __builtin_amdgcn_s_setprio(0);
        }
    };

    const int ksteps = K >> 6;
    stage(0, 0);
    __syncthreads();             // drains vmcnt(0): tile 0 visible
    int cur = 0;
    for (int t = 0; t + 1 < ksteps; ++t) {
        stage(cur ^ 1, (t + 1) << 6);   // in flight during current compute
        compute(cur);
        __syncthreads();         // drains vmcnt(0)+lgkmcnt(0): next tile ready,
        cur ^= 1;                // current tile's reads all retired
    }
    compute(cur);

    // epilogue: D mapping col=lane&15, row=(lane>>4)*4+reg
    #pragma unroll
    for (int i = 0; i < 8; ++i) {
        #pragma unroll
        for (int r2 = 0; r2 < 4; ++r2) {
            int m = m0 + wm * 128 + i * 16 + qd * 4 + r2;
            size_t rowbase = (out_mode == 0)
                ? (size_t)m * N
                : (size_t)(m & 63) * (TSTEP * N) + (size_t)(m >> 6) * N;
            #pragma unroll
            for (int j = 0; j < 4; ++j) {
                int n = n0 + wn * 64 + j * 16 + fr;
                float v = acc[i][j][r2];
                if (scale) v *= scale[n];
                if (bias)  v += bias[n];
                C[rowbase + n] = v;
            }
        }
    }
}

// ---------------------------------------------------------------------------
// fused GRU step: gh = h_prev @ W_hh^T (fp32, full-K dots), gates, h_new.
// One launch per step (replaces sgemm split-K8 + gru_ew pair).
// Block: 256 threads = 64 b x 4 jloc; grid: 256 blocks (j0 = blockIdx*4).
// W_hh slice (12 rows, bank-padded +4 floats) staged in LDS; h read float4
// from L2 (h is 256 KB, resident). Math identical to reference (fp32).
// ---------------------------------------------------------------------------
__global__ __launch_bounds__(256) void gru_step_kernel(
    const float* __restrict__ W_hh, const float* __restrict__ gi_t,
    const float* __restrict__ b_hh, const float* __restrict__ h_prev,
    float* __restrict__ h_new)
{
    __shared__ float Wl[12 * 1028];   // 12 rows x (1024+4 pad): rows 0-3 r, 4-7 z, 8-11 n
    const int tid = threadIdx.x;
    const int j0 = blockIdx.x * 4;

    // cooperative load of the 12 needed W_hh rows (coalesced float4)
    for (int p = tid; p < 3072; p += 256) {
        int row = p >> 8;          // 0..11
        int col4 = p & 255;
        int g = row >> 2, jl = row & 3;
        ((float4*)(Wl + row * 1028))[col4] =
            ((const float4*)(W_hh + ((size_t)g * GDIM + j0 + jl) * GDIM))[col4];
    }
    __syncthreads();

    const int b = tid >> 2, jl = tid & 3;
    const float* hrow = h_prev + (size_t)b * GDIM;
    const float* wr_p = Wl + jl * 1028;
    const float* wz_p = Wl + (4 + jl) * 1028;
    const float* wn_p = Wl + (8 + jl) * 1028;

    float ar = 0.f, az = 0.f, an = 0.f;
    #pragma unroll 4
    for (int k4 = 0; k4 < 256; ++k4) {
        float4 hv = ((const float4*)hrow)[k4];
        float4 w1 = ((const float4*)wr_p)[k4];
        float4 w2 = ((const float4*)wz_p)[k4];
        float4 w3 = ((const float4*)wn_p)[k4];
        ar = fmaf(hv.x, w1.x, ar); ar = fmaf(hv.y, w1.y, ar);
        ar = fmaf(hv.z, w1.z, ar); ar = fmaf(hv.w, w1.w, ar);
        az = fmaf(hv.x, w2.x, az); az = fmaf(hv.y, w2.y, az);
        az = fmaf(hv.z, w2.z, az); az = fmaf(hv.w, w2.w, az);
        an = fmaf(hv.x, w3.x, an); an = fmaf(hv.y, w3.y, an);
        an = fmaf(hv.z, w3.z, an); an = fmaf(hv.w, w3.w, an);
    }

    const int j = j0 + jl;
    const float* gi = gi_t + (size_t)b * G3;
    float ir = gi[j], iz = gi[j + GDIM], in_ = gi[j + 2 * GDIM];
    float hr = ar + b_hh[j];
    float hz = az + b_hh[j + GDIM];
    float hn = an + b_hh[j + 2 * GDIM];
    float r = 1.f / (1.f + expf(-(ir + hr)));
    float z = 1.f / (1.f + expf(-(iz + hz)));
    float n = tanhf(in_ + r * hn);
    h_new[(size_t)b * GDIM + j] = (1.f - z) * n + z * hrow[j];
}

// ---------------------------------------------------------------------------
// launch
// ---------------------------------------------------------------------------
extern "C" void kernel_launch(void* const* d_in, const int* in_sizes, int n_in,
                              void* d_out, int out_size, void* d_ws, size_t ws_size,
                              hipStream_t stream)
{
    const float* features = (const float*)d_in[0];
    const int*   ids      = (const int*)  d_in[1];
    const float* emb      = (const float*)d_in[2];
    const float* img_v    = (const float*)d_in[3];
    const float* img_g    = (const float*)d_in[4];
    const float* img_b    = (const float*)d_in[5];
    const float* W_ih     = (const float*)d_in[6];
    const float* W_hh     = (const float*)d_in[7];
    const float* b_ih     = (const float*)d_in[8];
    const float* b_hh     = (const float*)d_in[9];
    const float* fc_v     = (const float*)d_in[10];
    const float* fc_g     = (const float*)d_in[11];
    const float* fc_b     = (const float*)d_in[12];
    float* out = (float*)d_out;
    float* ws  = (float*)d_ws;

    // workspace layout (float offsets); fcv_bf overlays the dead phase-A region
    float* scale_img = ws;                          //      512
    float* scale_fc  = ws + 512;                    //    32000
    float* hs_buf    = ws + 32512;                  //  1376256  [21][64][1024]
    short* hs_bf     = (short*)(ws + 1408768);      //  1310720 shorts (655360 f)
    // phase-A region @ 2064128 (dead before fcv_bf conversion):
    float* x_all     = ws + 2064128;                //   655360  [20][64][512]
    short* x_bf      = (short*)(ws + 2719488);      //   655360 shorts
    short* wih_bf    = (short*)(ws + 3047168);      //  1572864 shorts
    float* gi_all    = ws + 3833600;                //  3932160  [1280][3072]
    short* fcv_bf    = (short*)(ws + 2064128);      // 32768000 shorts (overlay)
    // peak usage: 18448128 floats = ~70.4 MiB

    hipLaunchKernelGGL(scales_img_kernel, dim3(128), dim3(256), 0, stream,
                       img_v, img_g, scale_img);
    hipLaunchKernelGGL(img_embed_kernel, dim3(8192), dim3(256), 0, stream,
                       features, img_v, scale_img, img_b, x_all);
    hipLaunchKernelGGL(gather_kernel, dim3(2432), dim3(256), 0, stream,
                       ids, emb, x_all);
    hipLaunchKernelGGL(cvt_bf16_kernel, dim3((TSTEP * BATCH * EDIM / 4 + 255) / 256), dim3(256), 0, stream,
                       x_all, x_bf, TSTEP * BATCH * EDIM / 4);
    hipLaunchKernelGGL(cvt_bf16_kernel, dim3((G3 * EDIM / 4 + 255) / 256), dim3(256), 0, stream,
                       W_ih, wih_bf, G3 * EDIM / 4);
    hipMemsetAsync(hs_buf, 0, (size_t)BATCH * GDIM * sizeof(float), stream);

    // gi_all = x_bf @ wih_bf^T + b_ih   [1280, 3072], bf16 MFMA (128^2 tile)
    hipLaunchKernelGGL(mfma_gemm_kernel, dim3(G3 / 128, (TSTEP * BATCH) / 128, 1), dim3(256), 0, stream,
                       x_bf, wih_bf, gi_all, TSTEP * BATCH, G3, EDIM,
                       (const float*)nullptr, b_ih, 0);

    // GRU recurrence: 20 sequential fused steps (fp32)
    for (int t = 0; t < TSTEP; ++t) {
        const float* h_prev = hs_buf + (size_t)t * BATCH * GDIM;
        float* h_new        = hs_buf + (size_t)(t + 1) * BATCH * GDIM;
        hipLaunchKernelGGL(gru_step_kernel, dim3(GDIM / 4), dim3(256), 0, stream,
                           W_hh, gi_all + (size_t)t * BATCH * G3, b_hh, h_prev, h_new);
    }

    // hs -> bf16 (rows 1..20 of hs_buf)
    hipLaunchKernelGGL(cvt_bf16_kernel, dim3((TSTEP * BATCH * GDIM / 4 + 255) / 256), dim3(256), 0, stream,
                       hs_buf + (size_t)BATCH * GDIM, hs_bf, TSTEP * BATCH * GDIM / 4);
    // fc_v norms + bf16 convert (after GRU: fcv_bf overlays dead gi region)
    hipLaunchKernelGGL(fc_norm_cvt_kernel, dim3(VDIM), dim3(256), 0, stream,
                       fc_v, fc_g, fcv_bf, scale_fc);

    // preds = (hs_bf @ fcv_bf^T) * scale_fc + fc_b, permuted [B,T,V] store
    // 256^2 tile, grid = 125 n-tiles x 5 m-tiles = 625 blocks (1-D, swizzled)
    hipLaunchKernelGGL(mfma_gemm256_kernel,
                       dim3((VDIM / 256) * ((TSTEP * BATCH) / 256)), dim3(512), 0, stream,
                       hs_bf, fcv_bf, out, TSTEP * BATCH, VDIM, GDIM,
                       scale_fc, fc_b, 1);
}